// Round 2
// baseline (427.224 us; speedup 1.0000x reference)
//
#include <hip/hip_runtime.h>
#include <hip/hip_bf16.h>

typedef __attribute__((ext_vector_type(8))) short bf16x8;
typedef __attribute__((ext_vector_type(4))) float f32x4;

#define DEV static __device__ __forceinline__

DEV unsigned short f2bf(float f) {
    union { float f; unsigned int u; } v; v.f = f;
    return (unsigned short)((v.u + 0x7FFFu + ((v.u >> 16) & 1u)) >> 16);
}

DEV bf16x8 ld_bf8(const unsigned short* p) {
    return *reinterpret_cast<const bf16x8*>(p);
}

DEV f32x4 mfma16(bf16x8 a, bf16x8 b, f32x4 c) {
    return __builtin_amdgcn_mfma_f32_16x16x32_bf16(a, b, c, 0, 0, 0);
}

// ---------------- K0: f32 -> bf16 convert ----------------
__global__ void k_cvt(const float* __restrict__ s, unsigned short* __restrict__ d, int n) {
    int i = (blockIdx.x * blockDim.x + threadIdx.x) * 4;
    if (i >= n) return;
    float4 v = *reinterpret_cast<const float4*>(s + i);
    ushort4 o = { f2bf(v.x), f2bf(v.y), f2bf(v.z), f2bf(v.w) };
    *reinterpret_cast<ushort4*>(d + i) = o;
}

// ---------------- K1: qkv GEMM + bias + RoPE ----------------
// A = xb (4096x512 bf16), Bt = wqkvb (1536x512 bf16, row = out col, K contiguous)
// outputs: Qb,Kb (b,h,n,64) bf16 rope'd ; Vt (b,h,64,n) bf16
__global__ __launch_bounds__(256) void k_qkv(
    const unsigned short* __restrict__ xb, const unsigned short* __restrict__ wb,
    const float* __restrict__ bias,
    unsigned short* __restrict__ Qb, unsigned short* __restrict__ Kb,
    unsigned short* __restrict__ Vt)
{
    __shared__ unsigned short As[64][40];
    __shared__ unsigned short Bs[64][40];
    const int m0 = blockIdx.x * 64, c0 = blockIdx.y * 64;
    const int t = threadIdx.x;
    const int w = t >> 6, lane = t & 63, li = lane & 15, lg = lane >> 4;
    const int wr = w >> 1, wc = w & 1;
    f32x4 acc[2][2] = {};
    const int srow = t >> 2, spart = (t & 3) * 8;
    for (int kt = 0; kt < 512; kt += 32) {
        *reinterpret_cast<uint4*>(&As[srow][spart]) =
            *reinterpret_cast<const uint4*>(&xb[(size_t)(m0 + srow) * 512 + kt + spart]);
        *reinterpret_cast<uint4*>(&Bs[srow][spart]) =
            *reinterpret_cast<const uint4*>(&wb[(size_t)(c0 + srow) * 512 + kt + spart]);
        __syncthreads();
        bf16x8 af[2], bfr[2];
        #pragma unroll
        for (int mf = 0; mf < 2; mf++) af[mf] = ld_bf8(&As[wr*32 + mf*16 + li][lg*8]);
        #pragma unroll
        for (int nf = 0; nf < 2; nf++) bfr[nf] = ld_bf8(&Bs[wc*32 + nf*16 + li][lg*8]);
        #pragma unroll
        for (int mf = 0; mf < 2; mf++)
            #pragma unroll
            for (int nf = 0; nf < 2; nf++)
                acc[mf][nf] = mfma16(af[mf], bfr[nf], acc[mf][nf]);
        __syncthreads();
    }
    const int type = c0 >> 9;            // 0=q,1=k,2=v
    const int head = (c0 & 511) >> 6;
    const float b0 = bias[c0 + wc*32 + li];
    const float b1 = bias[c0 + wc*32 + 16 + li];
    float invf = 0.f;
    if (type < 2) invf = powf(10000.f, -(float)li * (1.f/16.f));
    #pragma unroll
    for (int mf = 0; mf < 2; mf++) {
        #pragma unroll
        for (int r = 0; r < 4; r++) {
            int grow = m0 + wr*32 + mf*16 + lg*4 + r;
            int tok = grow & 2047, bb = grow >> 11;
            float v0 = acc[mf][0][r] + b0;
            float v1 = acc[mf][1][r] + b1;
            if (type < 2) {
                float ang = (wc == 0 ? (float)(tok & 255) : (float)(tok >> 8)) * invf;
                float s, c;
                sincosf(ang, &s, &c);
                float r0 = v0 * c - v1 * s;
                float r1 = v0 * s + v1 * c;
                unsigned short* dst = (type == 0 ? Qb : Kb);
                size_t base = (((size_t)(bb*8 + head)) * 2048 + tok) * 64 + wc*32 + li;
                dst[base]      = f2bf(r0);
                dst[base + 16] = f2bf(r1);
            } else {
                size_t base = (((size_t)(bb*8 + head)) * 64 + wc*32 + li) * 2048 + tok;
                Vt[base]             = f2bf(v0);
                Vt[base + 16 * 2048] = f2bf(v1);
            }
        }
    }
}

// ---------------- K2: pass 1 — row stats (m, l) of mixed logits ----------------
// grid = b * n/16 = 256 blocks, 512 threads (8 waves = 8 heads)
__global__ __launch_bounds__(512) void k_stats(
    const unsigned short* __restrict__ Qb, const unsigned short* __restrict__ Kb,
    const float* __restrict__ w_pre, float* __restrict__ Mrow, float* __restrict__ Lrow)
{
    __shared__ float S[8][1040];   // 16 x (stride 65)
    const int blk = blockIdx.x;
    const int bb = blk >> 7, i0 = (blk & 127) << 4;
    const int w = threadIdx.x >> 6, lane = threadIdx.x & 63, li = lane & 15, lg = lane >> 4;
    float wpre[8];
    #pragma unroll
    for (int h = 0; h < 8; h++) wpre[h] = w_pre[w*8 + h] * 0.125f;  // fold scale
    const unsigned short* Qp = Qb + (((size_t)(bb*8 + w)) * 2048 + i0 + li) * 64;
    bf16x8 qa[2];
    qa[0] = ld_bf8(Qp + lg*8);
    qa[1] = ld_bf8(Qp + 32 + lg*8);
    const unsigned short* Kp = Kb + ((size_t)(bb*8 + w)) * 2048 * 64;
    float m_run = -1e30f, s_run = 0.f;
    for (int j0 = 0; j0 < 2048; j0 += 64) {
        f32x4 sa[4] = {};
        #pragma unroll
        for (int nf = 0; nf < 4; nf++)
            #pragma unroll
            for (int kk = 0; kk < 2; kk++) {
                bf16x8 kf = ld_bf8(Kp + (size_t)(j0 + nf*16 + li) * 64 + kk*32 + lg*8);
                sa[nf] = mfma16(qa[kk], kf, sa[nf]);
            }
        __syncthreads();   // prev iteration's mix reads done
        #pragma unroll
        for (int nf = 0; nf < 4; nf++)
            #pragma unroll
            for (int r = 0; r < 4; r++)
                S[w][(lg*4 + r) * 65 + nf*16 + li] = sa[nf][r];
        __syncthreads();
        float lp[16];
        float mloc = -1e30f;
        #pragma unroll
        for (int kk = 0; kk < 2; kk++)
            #pragma unroll
            for (int tt = 0; tt < 8; tt++) {
                int idx = li*65 + kk*32 + lg*8 + tt;
                float a = 0.f;
                #pragma unroll
                for (int h = 0; h < 8; h++) a += wpre[h] * S[h][idx];
                lp[kk*8 + tt] = a;
                mloc = fmaxf(mloc, a);
            }
        float mnew = fmaxf(m_run, mloc);
        float add = 0.f;
        #pragma unroll
        for (int e = 0; e < 16; e++) add += __expf(lp[e] - mnew);
        s_run = s_run * __expf(m_run - mnew) + add;
        m_run = mnew;
    }
    #pragma unroll
    for (int off = 16; off < 64; off <<= 1) {
        float mo = __shfl_xor(m_run, off);
        float so = __shfl_xor(s_run, off);
        float mn = fmaxf(m_run, mo);
        s_run = s_run * __expf(m_run - mn) + so * __expf(mo - mn);
        m_run = mn;
    }
    if (lg == 0) {
        size_t idx = ((size_t)(bb*8 + w)) * 2048 + i0 + li;
        Mrow[idx] = m_run;
        Lrow[idx] = s_run;
    }
}

// ---------------- K3: pass 2 — P, post-mix, PV ----------------
__global__ __launch_bounds__(512) void k_attn(
    const unsigned short* __restrict__ Qb, const unsigned short* __restrict__ Kb,
    const unsigned short* __restrict__ Vt,
    const float* __restrict__ w_pre, const float* __restrict__ w_post,
    const float* __restrict__ Mrow, const float* __restrict__ Lrow,
    unsigned short* __restrict__ AO)
{
    __shared__ float S[8][1040];
    const int blk = blockIdx.x;
    const int bb = blk >> 7, i0 = (blk & 127) << 4;
    const int w = threadIdx.x >> 6, lane = threadIdx.x & 63, li = lane & 15, lg = lane >> 4;
    float wpre[8], wpost[8];
    #pragma unroll
    for (int h = 0; h < 8; h++) {
        wpre[h]  = w_pre[w*8 + h] * 0.125f;
        wpost[h] = w_post[w*8 + h];
    }
    const unsigned short* Qp = Qb + (((size_t)(bb*8 + w)) * 2048 + i0 + li) * 64;
    bf16x8 qa[2];
    qa[0] = ld_bf8(Qp + lg*8);
    qa[1] = ld_bf8(Qp + 32 + lg*8);
    const unsigned short* Kp = Kb + ((size_t)(bb*8 + w)) * 2048 * 64;
    const unsigned short* Vp = Vt + ((size_t)(bb*8 + w)) * 64 * 2048;
    const float mh   = Mrow[((size_t)(bb*8 + w)) * 2048 + i0 + li];
    const float invl = 1.f / Lrow[((size_t)(bb*8 + w)) * 2048 + i0 + li];
    f32x4 oacc[4] = {};
    for (int j0 = 0; j0 < 2048; j0 += 64) {
        f32x4 sa[4] = {};
        #pragma unroll
        for (int nf = 0; nf < 4; nf++)
            #pragma unroll
            for (int kk = 0; kk < 2; kk++) {
                bf16x8 kf = ld_bf8(Kp + (size_t)(j0 + nf*16 + li) * 64 + kk*32 + lg*8);
                sa[nf] = mfma16(qa[kk], kf, sa[nf]);
            }
        __syncthreads();
        #pragma unroll
        for (int nf = 0; nf < 4; nf++)
            #pragma unroll
            for (int r = 0; r < 4; r++)
                S[w][(lg*4 + r) * 65 + nf*16 + li] = sa[nf][r];
        __syncthreads();
        // stage 1: per-head normalized P at lane elems (i=li, j=kk*32+lg*8+tt)
        float pv[16];
        #pragma unroll
        for (int kk = 0; kk < 2; kk++)
            #pragma unroll
            for (int tt = 0; tt < 8; tt++) {
                int idx = li*65 + kk*32 + lg*8 + tt;
                float a = 0.f;
                #pragma unroll
                for (int h = 0; h < 8; h++) a += wpre[h] * S[h][idx];
                pv[kk*8 + tt] = __expf(a - mh) * invl;
            }
        __syncthreads();
        #pragma unroll
        for (int kk = 0; kk < 2; kk++)
            #pragma unroll
            for (int tt = 0; tt < 8; tt++)
                S[w][li*65 + kk*32 + lg*8 + tt] = pv[kk*8 + tt];
        __syncthreads();
        // stage 2: post-mix -> bf16 A-frags, PV MFMA
        bf16x8 pa[2];
        #pragma unroll
        for (int kk = 0; kk < 2; kk++)
            #pragma unroll
            for (int tt = 0; tt < 8; tt++) {
                int idx = li*65 + kk*32 + lg*8 + tt;
                float a = 0.f;
                #pragma unroll
                for (int h = 0; h < 8; h++) a += wpost[h] * S[h][idx];
                pa[kk][tt] = (short)f2bf(a);
            }
        #pragma unroll
        for (int nf = 0; nf < 4; nf++)
            #pragma unroll
            for (int kk = 0; kk < 2; kk++) {
                bf16x8 vf = ld_bf8(Vp + (size_t)(nf*16 + li) * 2048 + j0 + kk*32 + lg*8);
                oacc[nf] = mfma16(pa[kk], vf, oacc[nf]);
            }
    }
    #pragma unroll
    for (int nf = 0; nf < 4; nf++)
        #pragma unroll
        for (int r = 0; r < 4; r++)
            AO[(((size_t)bb*2048) + i0 + lg*4 + r) * 512 + w*64 + nf*16 + li] = f2bf(oacc[nf][r]);
}

// ---------------- K4: output projection GEMM ----------------
__global__ __launch_bounds__(256) void k_out(
    const unsigned short* __restrict__ ab, const unsigned short* __restrict__ wb,
    const float* __restrict__ bias, float* __restrict__ out)
{
    __shared__ unsigned short As[64][40];
    __shared__ unsigned short Bs[64][40];
    const int m0 = blockIdx.x * 64, c0 = blockIdx.y * 64;
    const int t = threadIdx.x;
    const int w = t >> 6, lane = t & 63, li = lane & 15, lg = lane >> 4;
    const int wr = w >> 1, wc = w & 1;
    f32x4 acc[2][2] = {};
    const int srow = t >> 2, spart = (t & 3) * 8;
    for (int kt = 0; kt < 512; kt += 32) {
        *reinterpret_cast<uint4*>(&As[srow][spart]) =
            *reinterpret_cast<const uint4*>(&ab[(size_t)(m0 + srow) * 512 + kt + spart]);
        *reinterpret_cast<uint4*>(&Bs[srow][spart]) =
            *reinterpret_cast<const uint4*>(&wb[(size_t)(c0 + srow) * 512 + kt + spart]);
        __syncthreads();
        bf16x8 af[2], bfr[2];
        #pragma unroll
        for (int mf = 0; mf < 2; mf++) af[mf] = ld_bf8(&As[wr*32 + mf*16 + li][lg*8]);
        #pragma unroll
        for (int nf = 0; nf < 2; nf++) bfr[nf] = ld_bf8(&Bs[wc*32 + nf*16 + li][lg*8]);
        #pragma unroll
        for (int mf = 0; mf < 2; mf++)
            #pragma unroll
            for (int nf = 0; nf < 2; nf++)
                acc[mf][nf] = mfma16(af[mf], bfr[nf], acc[mf][nf]);
        __syncthreads();
    }
    #pragma unroll
    for (int mf = 0; mf < 2; mf++)
        #pragma unroll
        for (int nf = 0; nf < 2; nf++)
            #pragma unroll
            for (int r = 0; r < 4; r++) {
                int grow = m0 + wr*32 + mf*16 + lg*4 + r;
                int gcol = c0 + wc*32 + nf*16 + li;
                out[(size_t)grow * 512 + gcol] = acc[mf][nf][r] + bias[gcol];
            }
}

extern "C" void kernel_launch(void* const* d_in, const int* in_sizes, int n_in,
                              void* d_out, int out_size, void* d_ws, size_t ws_size,
                              hipStream_t stream)
{
    const float* x      = (const float*)d_in[0];
    const float* w_qkv  = (const float*)d_in[1];
    const float* b_qkv  = (const float*)d_in[2];
    const float* w_pre  = (const float*)d_in[3];
    const float* w_post = (const float*)d_in[4];
    const float* w_out  = (const float*)d_in[5];
    const float* b_out  = (const float*)d_in[6];
    float* out = (float*)d_out;

    char* ws = (char*)d_ws;
    unsigned short* xb    = (unsigned short*)(ws);              // 4,194,304 B
    unsigned short* wqkvb = (unsigned short*)(ws + 4194304);    // 1,572,864 B
    unsigned short* woutb = (unsigned short*)(ws + 5767168);    //   524,288 B
    unsigned short* Qb    = (unsigned short*)(ws + 6291456);    // 4,194,304 B
    unsigned short* Kb    = (unsigned short*)(ws + 10485760);   // 4,194,304 B
    unsigned short* Vt    = (unsigned short*)(ws + 14680064);   // 4,194,304 B
    unsigned short* AO    = (unsigned short*)(ws + 18874368);   // 4,194,304 B
    float* Mrow           = (float*)(ws + 23068672);            //   131,072 B
    float* Lrow           = (float*)(ws + 23199744);            //   131,072 B

    k_cvt<<<2097152/4/256, 256, 0, stream>>>(x, xb, 2097152);
    k_cvt<<<786432/4/256, 256, 0, stream>>>(w_qkv, wqkvb, 786432);
    k_cvt<<<262144/4/256, 256, 0, stream>>>(w_out, woutb, 262144);
    k_qkv<<<dim3(64, 24), 256, 0, stream>>>(xb, wqkvb, b_qkv, Qb, Kb, Vt);
    k_stats<<<256, 512, 0, stream>>>(Qb, Kb, w_pre, Mrow, Lrow);
    k_attn<<<256, 512, 0, stream>>>(Qb, Kb, Vt, w_pre, w_post, Mrow, Lrow, AO);
    k_out<<<dim3(64, 8), 256, 0, stream>>>(AO, woutb, b_out, out);
}

// Round 3
// 242.320 us; speedup vs baseline: 1.7631x; 1.7631x over previous
//
#include <hip/hip_runtime.h>
#include <hip/hip_bf16.h>

typedef __attribute__((ext_vector_type(8))) short bf16x8;
typedef __attribute__((ext_vector_type(4))) float f32x4;

#define DEV static __device__ __forceinline__

DEV unsigned short f2bf(float f) {
    union { float f; unsigned int u; } v; v.f = f;
    return (unsigned short)((v.u + 0x7FFFu + ((v.u >> 16) & 1u)) >> 16);
}
DEV float bf2f(unsigned short s) {
    union { unsigned int u; float f; } v; v.u = ((unsigned int)s) << 16; return v.f;
}
DEV bf16x8 ld_bf8(const unsigned short* p) {
    return *reinterpret_cast<const bf16x8*>(p);
}
DEV f32x4 mfma16(bf16x8 a, bf16x8 b, f32x4 c) {
    return __builtin_amdgcn_mfma_f32_16x16x32_bf16(a, b, c, 0, 0, 0);
}
// Weight fragment for the head-mix MFMA: 8x8 matrix, K padded 8->32, M/N padded 8->16.
// Lane li holds row/col li's 8 weights in k-slice lg==0; all other lanes zero.
DEV bf16x8 make_wfrag(const float* wmat, int li, int lg, float scale) {
    bf16x8 f = {};
    if (lg == 0 && li < 8) {
        #pragma unroll
        for (int t = 0; t < 8; t++) f[t] = (short)f2bf(wmat[li*8 + t] * scale);
    }
    return f;
}

// ---------------- K0: f32 -> bf16 convert ----------------
__global__ void k_cvt(const float* __restrict__ s, unsigned short* __restrict__ d, int n) {
    int i = (blockIdx.x * blockDim.x + threadIdx.x) * 4;
    if (i >= n) return;
    float4 v = *reinterpret_cast<const float4*>(s + i);
    ushort4 o = { f2bf(v.x), f2bf(v.y), f2bf(v.z), f2bf(v.w) };
    *reinterpret_cast<ushort4*>(d + i) = o;
}

// ---------------- K1: qkv GEMM + bias + RoPE (unchanged from r1) ----------------
__global__ __launch_bounds__(256) void k_qkv(
    const unsigned short* __restrict__ xb, const unsigned short* __restrict__ wb,
    const float* __restrict__ bias,
    unsigned short* __restrict__ Qb, unsigned short* __restrict__ Kb,
    unsigned short* __restrict__ Vt)
{
    __shared__ unsigned short As[64][40];
    __shared__ unsigned short Bs[64][40];
    const int m0 = blockIdx.x * 64, c0 = blockIdx.y * 64;
    const int t = threadIdx.x;
    const int w = t >> 6, lane = t & 63, li = lane & 15, lg = lane >> 4;
    const int wr = w >> 1, wc = w & 1;
    f32x4 acc[2][2] = {};
    const int srow = t >> 2, spart = (t & 3) * 8;
    for (int kt = 0; kt < 512; kt += 32) {
        *reinterpret_cast<uint4*>(&As[srow][spart]) =
            *reinterpret_cast<const uint4*>(&xb[(size_t)(m0 + srow) * 512 + kt + spart]);
        *reinterpret_cast<uint4*>(&Bs[srow][spart]) =
            *reinterpret_cast<const uint4*>(&wb[(size_t)(c0 + srow) * 512 + kt + spart]);
        __syncthreads();
        bf16x8 af[2], bfr[2];
        #pragma unroll
        for (int mf = 0; mf < 2; mf++) af[mf] = ld_bf8(&As[wr*32 + mf*16 + li][lg*8]);
        #pragma unroll
        for (int nf = 0; nf < 2; nf++) bfr[nf] = ld_bf8(&Bs[wc*32 + nf*16 + li][lg*8]);
        #pragma unroll
        for (int mf = 0; mf < 2; mf++)
            #pragma unroll
            for (int nf = 0; nf < 2; nf++)
                acc[mf][nf] = mfma16(af[mf], bfr[nf], acc[mf][nf]);
        __syncthreads();
    }
    const int type = c0 >> 9;
    const int head = (c0 & 511) >> 6;
    const float b0 = bias[c0 + wc*32 + li];
    const float b1 = bias[c0 + wc*32 + 16 + li];
    float invf = 0.f;
    if (type < 2) invf = powf(10000.f, -(float)li * (1.f/16.f));
    #pragma unroll
    for (int mf = 0; mf < 2; mf++) {
        #pragma unroll
        for (int r = 0; r < 4; r++) {
            int grow = m0 + wr*32 + mf*16 + lg*4 + r;
            int tok = grow & 2047, bb = grow >> 11;
            float v0 = acc[mf][0][r] + b0;
            float v1 = acc[mf][1][r] + b1;
            if (type < 2) {
                float ang = (wc == 0 ? (float)(tok & 255) : (float)(tok >> 8)) * invf;
                float s, c;
                sincosf(ang, &s, &c);
                float r0 = v0 * c - v1 * s;
                float r1 = v0 * s + v1 * c;
                unsigned short* dst = (type == 0 ? Qb : Kb);
                size_t base = (((size_t)(bb*8 + head)) * 2048 + tok) * 64 + wc*32 + li;
                dst[base]      = f2bf(r0);
                dst[base + 16] = f2bf(r1);
            } else {
                size_t base = (((size_t)(bb*8 + head)) * 64 + wc*32 + li) * 2048 + tok;
                Vt[base]             = f2bf(v0);
                Vt[base + 16 * 2048] = f2bf(v1);
            }
        }
    }
}

// ---------------- K2: pass 1 — l[h][i] = sum_j exp(L'[h,i,j])  (no max; logits bounded) ----
// grid = 512: blk = [bb(1b) | i-tile(7b) | jh(1b)], 512 threads = 8 waves = 8 heads
__global__ __launch_bounds__(512, 4) void k_lsum(
    const unsigned short* __restrict__ Qb, const unsigned short* __restrict__ Kb,
    const float* __restrict__ w_pre, float* __restrict__ Lp)
{
    __shared__ unsigned short Lt[8192];   // element-major logits: Lt[e*8 + h]
    const int blk = blockIdx.x;
    const int jh = blk & 1, it = (blk >> 1) & 127, bb = blk >> 8;
    const int i0 = it * 16;
    const int tid = threadIdx.x, w = tid >> 6, lane = tid & 63, li = lane & 15, lg = lane >> 4;
    bf16x8 W1f = make_wfrag(w_pre, li, lg, 0.125f);
    const unsigned short* Qp = Qb + (((size_t)(bb*8 + w)) * 2048 + i0 + li) * 64;
    bf16x8 qa0 = ld_bf8(Qp + lg*8), qa1 = ld_bf8(Qp + 32 + lg*8);
    const unsigned short* Kp = Kb + ((size_t)(bb*8 + w)) * 2048 * 64;
    const f32x4 zero = {};
    float lacc0 = 0.f, lacc1 = 0.f;
    for (int t = 0; t < 16; t++) {
        int j0 = jh*1024 + t*64;
        f32x4 sa[4] = {};
        #pragma unroll
        for (int nf = 0; nf < 4; nf++) {
            bf16x8 kf0 = ld_bf8(Kp + (size_t)(j0 + nf*16 + li) * 64 + lg*8);
            bf16x8 kf1 = ld_bf8(Kp + (size_t)(j0 + nf*16 + li) * 64 + 32 + lg*8);
            sa[nf] = mfma16(qa0, kf0, sa[nf]);
            sa[nf] = mfma16(qa1, kf1, sa[nf]);
        }
        #pragma unroll
        for (int nf = 0; nf < 4; nf++)
            #pragma unroll
            for (int r = 0; r < 4; r++)
                Lt[((lg*4 + r)*64 + nf*16 + li)*8 + w] = f2bf(sa[nf][r]);
        __syncthreads();
        // mix via MFMA: D[e, g] = sum_h Lt[e,h] * W1[g,h]; wave w owns i-rows {2w, 2w+1}
        #pragma unroll
        for (int x = 0; x < 2; x++) {
            int i = 2*w + x;
            float s = 0.f;
            #pragma unroll
            for (int jj = 0; jj < 4; jj++) {
                int e0 = i*64 + jj*16;
                bf16x8 af = {};
                if (lg == 0) af = *(const bf16x8*)&Lt[(e0 + li)*8];
                f32x4 d = mfma16(af, W1f, zero);
                #pragma unroll
                for (int r = 0; r < 4; r++) s += __expf(d[r]);
            }
            if (x == 0) lacc0 += s; else lacc1 += s;
        }
        __syncthreads();
    }
    lacc0 += __shfl_xor(lacc0, 16); lacc0 += __shfl_xor(lacc0, 32);
    lacc1 += __shfl_xor(lacc1, 16); lacc1 += __shfl_xor(lacc1, 32);
    if (li < 8 && lg == 0) {
        float* Lpw = Lp + (size_t)jh * 32768;
        size_t base = (size_t)bb*2048 + i0;
        Lpw[(base + 2*w + 0)*8 + li] = lacc0;
        Lpw[(base + 2*w + 1)*8 + li] = lacc1;
    }
}

// ---------------- K3: pass 2 — P, post-mix (MFMA), PV ----------------
__global__ __launch_bounds__(512, 4) void k_attn(
    const unsigned short* __restrict__ Qb, const unsigned short* __restrict__ Kb,
    const unsigned short* __restrict__ Vt,
    const float* __restrict__ w_pre, const float* __restrict__ w_post,
    const float* __restrict__ Lp,
    unsigned short* __restrict__ AOp0, unsigned short* __restrict__ AOp1)
{
    __shared__ unsigned short Lt[8192];
    __shared__ unsigned short Pt[8192];
    __shared__ unsigned short Ah[8 * 1168];   // [g][i][72j] bf16, padded strides
    __shared__ float Llds[128];               // invl[i][h]
    const int blk = blockIdx.x;
    const int jh = blk & 1, it = (blk >> 1) & 127, bb = blk >> 8;
    const int i0 = it * 16;
    const int tid = threadIdx.x, w = tid >> 6, lane = tid & 63, li = lane & 15, lg = lane >> 4;
    bf16x8 W1f = make_wfrag(w_pre, li, lg, 0.125f);
    bf16x8 W2f = make_wfrag(w_post, li, lg, 1.0f);
    if (tid < 128) {
        size_t g = ((size_t)bb*2048 + i0 + (tid >> 3)) * 8 + (tid & 7);
        Llds[tid] = 1.0f / (Lp[g] + Lp[32768 + g]);
    }
    const unsigned short* Qp = Qb + (((size_t)(bb*8 + w)) * 2048 + i0 + li) * 64;
    bf16x8 qa0 = ld_bf8(Qp + lg*8), qa1 = ld_bf8(Qp + 32 + lg*8);
    const unsigned short* Kp = Kb + ((size_t)(bb*8 + w)) * 2048 * 64;
    const unsigned short* Vp = Vt + ((size_t)(bb*8 + w)) * 64 * 2048;
    __syncthreads();
    const int lgc = lg & 1;
    f32x4 invlA = *(const f32x4*)&Llds[(2*w + 0)*8 + lgc*4];
    f32x4 invlB = *(const f32x4*)&Llds[(2*w + 1)*8 + lgc*4];
    const f32x4 zero = {};
    f32x4 oacc[4] = {};
    for (int t = 0; t < 16; t++) {
        int j0 = jh*1024 + t*64;
        // --- QK^T ---
        f32x4 sa[4] = {};
        #pragma unroll
        for (int nf = 0; nf < 4; nf++) {
            bf16x8 kf0 = ld_bf8(Kp + (size_t)(j0 + nf*16 + li) * 64 + lg*8);
            bf16x8 kf1 = ld_bf8(Kp + (size_t)(j0 + nf*16 + li) * 64 + 32 + lg*8);
            sa[nf] = mfma16(qa0, kf0, sa[nf]);
            sa[nf] = mfma16(qa1, kf1, sa[nf]);
        }
        #pragma unroll
        for (int nf = 0; nf < 4; nf++)
            #pragma unroll
            for (int r = 0; r < 4; r++)
                Lt[((lg*4 + r)*64 + nf*16 + li)*8 + w] = f2bf(sa[nf][r]);
        __syncthreads();
        // --- stage1: pre-mix (MFMA) + exp + normalize -> Pt ---
        #pragma unroll
        for (int x = 0; x < 2; x++) {
            int i = 2*w + x;
            f32x4 invl = x ? invlB : invlA;
            #pragma unroll
            for (int jj = 0; jj < 4; jj++) {
                int e0 = i*64 + jj*16;
                bf16x8 bf = {};
                if (lg == 0) bf = *(const bf16x8*)&Lt[(e0 + li)*8];
                f32x4 d = mfma16(W1f, bf, zero);   // D[g, e]: g = lg*4+r, e = e0+li
                if (lg < 2) {
                    unsigned p01 = (unsigned)f2bf(__expf(d[0]) * invl[0])
                                 | ((unsigned)f2bf(__expf(d[1]) * invl[1]) << 16);
                    unsigned p23 = (unsigned)f2bf(__expf(d[2]) * invl[2])
                                 | ((unsigned)f2bf(__expf(d[3]) * invl[3]) << 16);
                    uint2 pk = { p01, p23 };
                    *(uint2*)&Pt[(e0 + li)*8 + lg*4] = pk;
                }
            }
        }
        __syncthreads();
        // --- stage2: post-mix (MFMA) -> Ah ---
        #pragma unroll
        for (int x = 0; x < 2; x++) {
            int i = 2*w + x;
            #pragma unroll
            for (int jj = 0; jj < 4; jj++) {
                int e0 = i*64 + jj*16;
                bf16x8 af = {};
                if (lg == 0) af = *(const bf16x8*)&Pt[(e0 + li)*8];
                f32x4 d = mfma16(af, W2f, zero);   // D[e, g2]: e = e0+lg*4+r, g2 = li
                if (li < 8) {
                    ushort4 o = { f2bf(d[0]), f2bf(d[1]), f2bf(d[2]), f2bf(d[3]) };
                    *(ushort4*)&Ah[li*1168 + i*72 + jj*16 + lg*4] = o;
                }
            }
        }
        __syncthreads();
        // --- PV ---
        #pragma unroll
        for (int kk = 0; kk < 2; kk++) {
            bf16x8 pa = *(const bf16x8*)&Ah[w*1168 + li*72 + kk*32 + lg*8];
            #pragma unroll
            for (int nf = 0; nf < 4; nf++) {
                bf16x8 vf = ld_bf8(Vp + (size_t)(nf*16 + li) * 2048 + j0 + kk*32 + lg*8);
                oacc[nf] = mfma16(pa, vf, oacc[nf]);
            }
        }
    }
    unsigned short* ao = jh ? AOp1 : AOp0;
    #pragma unroll
    for (int nf = 0; nf < 4; nf++)
        #pragma unroll
        for (int r = 0; r < 4; r++)
            ao[((size_t)bb*2048 + i0 + lg*4 + r)*512 + w*64 + nf*16 + li] = f2bf(oacc[nf][r]);
}

// ---------------- K4: output projection GEMM (sums the two j-half partials) --------
__global__ __launch_bounds__(256) void k_out(
    const unsigned short* __restrict__ a0, const unsigned short* __restrict__ a1,
    const unsigned short* __restrict__ wb, const float* __restrict__ bias,
    float* __restrict__ out)
{
    __shared__ unsigned short As[64][40];
    __shared__ unsigned short Bs[64][40];
    const int m0 = blockIdx.x * 64, c0 = blockIdx.y * 64;
    const int t = threadIdx.x;
    const int w = t >> 6, lane = t & 63, li = lane & 15, lg = lane >> 4;
    const int wr = w >> 1, wc = w & 1;
    f32x4 acc[2][2] = {};
    const int srow = t >> 2, spart = (t & 3) * 8;
    for (int kt = 0; kt < 512; kt += 32) {
        size_t aidx = (size_t)(m0 + srow) * 512 + kt + spart;
        uint4 ua = *(const uint4*)&a0[aidx];
        uint4 ub = *(const uint4*)&a1[aidx];
        const unsigned short* pa = (const unsigned short*)&ua;
        const unsigned short* pb = (const unsigned short*)&ub;
        unsigned short us[8];
        #pragma unroll
        for (int q = 0; q < 8; q++) us[q] = f2bf(bf2f(pa[q]) + bf2f(pb[q]));
        *reinterpret_cast<uint4*>(&As[srow][spart]) = *(const uint4*)us;
        *reinterpret_cast<uint4*>(&Bs[srow][spart]) =
            *reinterpret_cast<const uint4*>(&wb[(size_t)(c0 + srow) * 512 + kt + spart]);
        __syncthreads();
        bf16x8 af[2], bfr[2];
        #pragma unroll
        for (int mf = 0; mf < 2; mf++) af[mf] = ld_bf8(&As[wr*32 + mf*16 + li][lg*8]);
        #pragma unroll
        for (int nf = 0; nf < 2; nf++) bfr[nf] = ld_bf8(&Bs[wc*32 + nf*16 + li][lg*8]);
        #pragma unroll
        for (int mf = 0; mf < 2; mf++)
            #pragma unroll
            for (int nf = 0; nf < 2; nf++)
                acc[mf][nf] = mfma16(af[mf], bfr[nf], acc[mf][nf]);
        __syncthreads();
    }
    #pragma unroll
    for (int mf = 0; mf < 2; mf++)
        #pragma unroll
        for (int nf = 0; nf < 2; nf++)
            #pragma unroll
            for (int r = 0; r < 4; r++) {
                int grow = m0 + wr*32 + mf*16 + lg*4 + r;
                int gcol = c0 + wc*32 + nf*16 + li;
                out[(size_t)grow * 512 + gcol] = acc[mf][nf][r] + bias[gcol];
            }
}

extern "C" void kernel_launch(void* const* d_in, const int* in_sizes, int n_in,
                              void* d_out, int out_size, void* d_ws, size_t ws_size,
                              hipStream_t stream)
{
    const float* x      = (const float*)d_in[0];
    const float* w_qkv  = (const float*)d_in[1];
    const float* b_qkv  = (const float*)d_in[2];
    const float* w_pre  = (const float*)d_in[3];
    const float* w_post = (const float*)d_in[4];
    const float* w_out  = (const float*)d_in[5];
    const float* b_out  = (const float*)d_in[6];
    float* out = (float*)d_out;

    char* ws = (char*)d_ws;
    unsigned short* xb    = (unsigned short*)(ws);              // 4 MB (dead after k_qkv)
    unsigned short* AOp1  = (unsigned short*)(ws);              // 4 MB (overlays xb)
    unsigned short* wqkvb = (unsigned short*)(ws + 4194304);    // 1.5 MB
    unsigned short* woutb = (unsigned short*)(ws + 5767168);    // 0.5 MB
    unsigned short* Qb    = (unsigned short*)(ws + 6291456);    // 4 MB
    unsigned short* Kb    = (unsigned short*)(ws + 10485760);   // 4 MB
    unsigned short* Vt    = (unsigned short*)(ws + 14680064);   // 4 MB
    unsigned short* AOp0  = (unsigned short*)(ws + 18874368);   // 4 MB
    float* Lp             = (float*)(ws + 23068672);            // 2 x 128 KB

    k_cvt<<<2048, 256, 0, stream>>>(x, xb, 2097152);
    k_cvt<<<768, 256, 0, stream>>>(w_qkv, wqkvb, 786432);
    k_cvt<<<256, 256, 0, stream>>>(w_out, woutb, 262144);
    k_qkv<<<dim3(64, 24), 256, 0, stream>>>(xb, wqkvb, b_qkv, Qb, Kb, Vt);
    k_lsum<<<512, 512, 0, stream>>>(Qb, Kb, w_pre, Lp);
    k_attn<<<512, 512, 0, stream>>>(Qb, Kb, Vt, w_pre, w_post, Lp, AOp0, AOp1);
    k_out<<<dim3(64, 8), 256, 0, stream>>>(AOp0, AOp1, woutb, b_out, out);
}